// Round 5
// baseline (160.553 us; speedup 1.0000x reference)
//
#include <hip/hip_runtime.h>

// AnomalyAttention: B=16, L=512, H=8, E=D=64. f32 in/out, bf16 MFMA compute.
// out = [ g*(e@V)/E + (1-g)*(p@V)/(P+1e-8) ] / (Sf + 1e-8),
//   Sf = g + (1-g)*P/(P+1e-8); e = exp(QK^T/8) causal (no max-sub needed),
//   p = Gaussian prior; E,P per-row sums of the bf16-rounded e,p.
// KEY: sigma <= 2.00002 -> prior underflows to EXACT f32 zero for |l-s|>=65,
// so prior work is restricted to s-tiles {t-1,t,t+1} and the tile loop stops
// at t+1 — bit-identical to the full-row reference computation.
// Block = 64 q-rows (4 waves x 16), s-tiles of 64.
// MFMA 16x16x32 bf16 layouts (m120-verified):
//   A[m=lane&15][k=quad*8+j]  B[k=quad*8+j][n=lane&15]  D[row=quad*4+reg][col=lane&15]

#define B_ 16
#define L_ 512
#define H_ 8

#define KST 72   // K LDS row stride (shorts): 144B, 16B-aligned
#define VST 72   // V^T LDS row stride (shorts)
#define WST 68   // W_ep LDS row stride (dwords): 272B, 16B-aligned

typedef __attribute__((ext_vector_type(8))) short bf16x8;
typedef __attribute__((ext_vector_type(4))) float f32x4;
union FR { bf16x8 v; unsigned u[4]; };

__device__ __forceinline__ unsigned bfbits(float x) {
    union { float f; unsigned u; } c; c.f = x;
    return (c.u + 0x7FFFu + ((c.u >> 16) & 1u)) >> 16;
}
__device__ __forceinline__ float bfval(unsigned b) {
    union { unsigned u; float f; } c; c.u = b << 16; return c.f;
}
__device__ __forceinline__ float wsum16(float v) {
    #pragma unroll
    for (int off = 1; off < 16; off <<= 1) v += __shfl_xor(v, off, 64);
    return v;
}

__global__ __launch_bounds__(256, 4) void anomaly_attn(
    const float* __restrict__ Q, const float* __restrict__ K,
    const float* __restrict__ V, const float* __restrict__ Sig,
    const float* __restrict__ Gate, float* __restrict__ Out)
{
    __shared__ unsigned short Klds[64 * KST];   // 9216 B
    __shared__ unsigned short Vlds[64 * VST];   // 9216 B (V^T, granule-swizzled)
    __shared__ unsigned       Wep[4 * 16 * WST];// 17408 B (packed e|p<<16, bf16)

    const int tid  = threadIdx.x;
    const int lane = tid & 63;
    const int wid  = tid >> 6;
    const int quad = lane >> 4;
    const int c16  = lane & 15;

    const int idx = blockIdx.x;           // t*128 + bh (XCD-affine for same t)
    const int bh  = idx & 127;
    const int t   = idx >> 7;
    const int h   = bh & 7, b = bh >> 3;
    const int l0  = t * 64;
    const int l0w = l0 + wid * 16;

    const size_t bh_off = ((size_t)b * L_ * H_ + h) * 64;
    const float* __restrict__ Qb = Q + bh_off;
    const float* __restrict__ Kb = K + bh_off;
    const float* __restrict__ Vb = V + bh_off;

    // ---- Q A-frags (k = 64 -> 2 k-steps), held in registers ----
    bf16x8 qf[2];
    {
        const float* qrow = Qb + (size_t)(l0w + c16) * 512;
        #pragma unroll
        for (int ks = 0; ks < 2; ++ks) {
            const float4 a = *(const float4*)(qrow + ks * 32 + quad * 8);
            const float4 c = *(const float4*)(qrow + ks * 32 + quad * 8 + 4);
            FR f;
            f.u[0] = bfbits(a.x) | (bfbits(a.y) << 16);
            f.u[1] = bfbits(a.z) | (bfbits(a.w) << 16);
            f.u[2] = bfbits(c.x) | (bfbits(c.y) << 16);
            f.u[3] = bfbits(c.z) | (bfbits(c.w) << 16);
            qf[ks] = f.v;
        }
    }

    // ---- per-row prior constants (rows l0w + quad*4 + reg) ----
    float invs[4], i2s2[4], eP[4], pP[4];
    #pragma unroll
    for (int reg = 0; reg < 4; ++reg) {
        const int l = l0w + quad * 4 + reg;
        const float sgv = Sig[((size_t)b * L_ + l) * H_ + h];
        float sg = 1.f / (1.f + __expf(-5.f * sgv)) + 1e-5f;
        sg = exp2f(sg * 1.5849625007211562f) - 1.f;       // 3^sg - 1
        invs[reg] = 0.3989422804014327f / sg;
        i2s2[reg] = (0.5f / (sg * sg)) * 1.44269504088896f;  // folded log2(e)
        eP[reg] = 0.f; pP[reg] = 0.f;
    }

    f32x4 accA[4], accB[4];
    #pragma unroll
    for (int nt = 0; nt < 4; ++nt) { accA[nt] = (f32x4)0.f; accB[nt] = (f32x4)0.f; }

    // staging maps
    const int kr  = tid >> 2, kcb = tid & 3;   // K: row, 16-col chunk
    const int srp = tid >> 3, scb = tid & 7;   // V: s-row-pair, 8-col chunk

    unsigned* __restrict__ wrow = &Wep[wid * 16 * WST];  // wave-private

    const int tmax = (t < 7) ? (t + 1) : 7;
    for (int tile = 0; tile <= tmax; ++tile) {
        const int s0 = tile * 64;
        const bool live = (tile <= t);       // e-tiles (causal)
        const bool band = (tile >= t - 1);   // prior band (|l-s|<=127 possible)
        const bool diag = (tile == t);
        __syncthreads();   // prior tile's K/V reads complete

        if (live) {  // stage K tile -> bf16 LDS [s][e]
            const float* kp = Kb + (size_t)(s0 + kr) * 512 + kcb * 16;
            const float4 a = ((const float4*)kp)[0];
            const float4 c = ((const float4*)kp)[1];
            const float4 d = ((const float4*)kp)[2];
            const float4 e = ((const float4*)kp)[3];
            uint4 w0, w1;
            w0.x = bfbits(a.x) | (bfbits(a.y) << 16);
            w0.y = bfbits(a.z) | (bfbits(a.w) << 16);
            w0.z = bfbits(c.x) | (bfbits(c.y) << 16);
            w0.w = bfbits(c.z) | (bfbits(c.w) << 16);
            w1.x = bfbits(d.x) | (bfbits(d.y) << 16);
            w1.y = bfbits(d.z) | (bfbits(d.w) << 16);
            w1.z = bfbits(e.x) | (bfbits(e.y) << 16);
            w1.w = bfbits(e.z) | (bfbits(e.w) << 16);
            uint4* dst = (uint4*)&Klds[kr * KST + kcb * 16];
            dst[0] = w0; dst[1] = w1;
        }
        {   // stage V tile -> bf16 LDS transposed [d][s], XOR-granule swizzle
            const float* vp = Vb + (size_t)(s0 + 2 * srp) * 512 + scb * 8;
            const float4 a0 = ((const float4*)vp)[0];
            const float4 a1 = ((const float4*)vp)[1];
            const float4 b0 = ((const float4*)(vp + 512))[0];
            const float4 b1 = ((const float4*)(vp + 512))[1];
            const float lo[8] = {a0.x,a0.y,a0.z,a0.w,a1.x,a1.y,a1.z,a1.w};
            const float hi[8] = {b0.x,b0.y,b0.z,b0.w,b1.x,b1.y,b1.z,b1.w};
            const int gp  = (srp >> 2) ^ scb;   // swizzled granule (8 shorts)
            const int rpl = srp & 3;            // dword within granule
            #pragma unroll
            for (int i = 0; i < 8; ++i) {
                const int d = scb * 8 + i;
                unsigned* p = (unsigned*)&Vlds[d * VST + (gp << 3)];
                p[rpl] = bfbits(lo[i]) | (bfbits(hi[i]) << 16);
            }
        }
        __syncthreads();

        // ---- scores MFMA + elementwise -> packed (e,p) into W_ep ----
        if (live) {
            f32x4 sacc[4];
            #pragma unroll
            for (int nt = 0; nt < 4; ++nt) sacc[nt] = (f32x4)0.f;
            #pragma unroll
            for (int nt = 0; nt < 4; ++nt) {
                #pragma unroll
                for (int ks = 0; ks < 2; ++ks) {
                    const bf16x8 kf = *(const bf16x8*)&Klds[(nt*16 + c16)*KST + ks*32 + quad*8];
                    sacc[nt] = __builtin_amdgcn_mfma_f32_16x16x32_bf16(qf[ks], kf, sacc[nt], 0, 0, 0);
                }
            }
            if (band) {   // tiles t-1, t: e + prior
                #pragma unroll
                for (int nt = 0; nt < 4; ++nt) {
                    const int scol = s0 + nt * 16 + c16;
                    #pragma unroll
                    for (int reg = 0; reg < 4; ++reg) {
                        const int lrow = l0w + quad * 4 + reg;
                        float e = exp2f(sacc[nt][reg] * 0.180336880110323f); // exp(s/8)
                        if (diag && scol > lrow) e = 0.f;
                        const float dd = (float)(lrow - scol);
                        const float p = invs[reg] * exp2f(-dd * dd * i2s2[reg]);
                        const unsigned eb = bfbits(e), pb = bfbits(p);
                        eP[reg] += bfval(eb);
                        pP[reg] += bfval(pb);
                        wrow[(quad*4 + reg)*WST + nt*16 + c16] = eb | (pb << 16);
                    }
                }
            } else {      // tiles < t-1: e only (prior == exact f32 zero there)
                #pragma unroll
                for (int nt = 0; nt < 4; ++nt) {
                    #pragma unroll
                    for (int reg = 0; reg < 4; ++reg) {
                        float e = exp2f(sacc[nt][reg] * 0.180336880110323f);
                        const unsigned eb = bfbits(e);
                        eP[reg] += bfval(eb);
                        wrow[(quad*4 + reg)*WST + nt*16 + c16] = eb;
                    }
                }
            }
        } else {  // tile == t+1: prior-only (upper band, e masked out)
            #pragma unroll
            for (int nt = 0; nt < 4; ++nt) {
                const int scol = s0 + nt * 16 + c16;
                #pragma unroll
                for (int reg = 0; reg < 4; ++reg) {
                    const int lrow = l0w + quad * 4 + reg;
                    const float dd = (float)(lrow - scol);
                    const float p = invs[reg] * exp2f(-dd * dd * i2s2[reg]);
                    const unsigned pb = bfbits(p);
                    pP[reg] += bfval(pb);
                    wrow[(quad*4 + reg)*WST + nt*16 + c16] = pb << 16;
                }
            }
        }
        asm volatile("s_waitcnt lgkmcnt(0)" ::: "memory");

        // ---- PV MFMAs: A = W_ep rows (A-layout re-read), B = V^T tiles ----
        bf16x8 ef[2], pf[2];
        #pragma unroll
        for (int ks = 0; ks < 2; ++ks) {
            const unsigned* src = &wrow[c16 * WST + ks * 32 + quad * 8];
            const uint4 p0 = *(const uint4*)src;
            const uint4 p1 = *((const uint4*)src + 1);
            if (live) {
                FR fe;
                fe.u[0] = (p0.x & 0xFFFFu) | (p0.y << 16);
                fe.u[1] = (p0.z & 0xFFFFu) | (p0.w << 16);
                fe.u[2] = (p1.x & 0xFFFFu) | (p1.y << 16);
                fe.u[3] = (p1.z & 0xFFFFu) | (p1.w << 16);
                ef[ks] = fe.v;
            }
            if (band) {
                FR fp;
                fp.u[0] = (p0.x >> 16) | (p0.y & 0xFFFF0000u);
                fp.u[1] = (p0.z >> 16) | (p0.w & 0xFFFF0000u);
                fp.u[2] = (p1.x >> 16) | (p1.y & 0xFFFF0000u);
                fp.u[3] = (p1.z >> 16) | (p1.w & 0xFFFF0000u);
                pf[ks] = fp.v;
            }
        }
        #pragma unroll
        for (int nt = 0; nt < 4; ++nt) {
            const int d   = nt * 16 + c16;
            const int dg7 = (d >> 3) & 7;
            #pragma unroll
            for (int ks = 0; ks < 2; ++ks) {
                const int g2 = ((ks << 2) + quad) ^ dg7;
                const bf16x8 vf = *(const bf16x8*)&Vlds[d * VST + (g2 << 3)];
                if (live) accA[nt] = __builtin_amdgcn_mfma_f32_16x16x32_bf16(ef[ks], vf, accA[nt], 0, 0, 0);
                if (band) accB[nt] = __builtin_amdgcn_mfma_f32_16x16x32_bf16(pf[ks], vf, accB[nt], 0, 0, 0);
            }
        }
        asm volatile("s_waitcnt lgkmcnt(0)" ::: "memory");
    }

    // ---- epilogue ----
    float g = Gate[h];
    g = 1.f / (1.f + __expf(-g));
    float cA[4], cB[4], nf[4];
    #pragma unroll
    for (int reg = 0; reg < 4; ++reg) {
        const float E = wsum16(eP[reg]);
        const float P = wsum16(pP[reg]);
        cA[reg] = g / E;
        cB[reg] = (1.f - g) / (P + 1e-8f);
        const float Sf = g + (1.f - g) * (P / (P + 1e-8f));
        nf[reg] = 1.f / (Sf + 1e-8f);
    }
    #pragma unroll
    for (int reg = 0; reg < 4; ++reg) {
        const size_t ro = bh_off + (size_t)(l0w + quad * 4 + reg) * 512;
        #pragma unroll
        for (int nt = 0; nt < 4; ++nt) {
            const float o = (cA[reg] * accA[nt][reg] + cB[reg] * accB[nt][reg]) * nf[reg];
            Out[ro + nt * 16 + c16] = o;
        }
    }
}

extern "C" void kernel_launch(void* const* d_in, const int* in_sizes, int n_in,
                              void* d_out, int out_size, void* d_ws, size_t ws_size,
                              hipStream_t stream) {
    const float* Q    = (const float*)d_in[0];
    const float* K    = (const float*)d_in[1];
    const float* V    = (const float*)d_in[2];
    const float* Sig  = (const float*)d_in[3];
    const float* Gate = (const float*)d_in[4];
    // d_in[5] = attn_mask: deterministic causal triu — not read.
    float* Out = (float*)d_out;

    dim3 grid(8 * B_ * H_);   // 1024 blocks: idx = t*128 + bh
    anomaly_attn<<<grid, 256, 0, stream>>>(Q, K, V, Sig, Gate, Out);
}

// Round 6
// 122.357 us; speedup vs baseline: 1.3122x; 1.3122x over previous
//
#include <hip/hip_runtime.h>

// AnomalyAttention: B=16, L=512, H=8, E=D=64. f32 in/out, bf16 MFMA compute.
// Transposed formulation: S^T = K.Q^T (D: row=s, col=l), out^T = V^T.W^T
// (D: row=d, col=l). W (e,p) round-trips LDS as packed bf16 dwords with NO
// bit-unpacking: writer D-layout dwords == reader B-operand dwords.
// out = [ g*(e@V)/E + (1-g)*(p@V)/(P+1e-8) ] / (Sf+1e-8), E,P = sums of the
// truncated-bf16 e,p (consistent with MFMA operands). Prior exact-underflow
// band: |l-s|>=65 -> f32 zero. Uniform 8-tile loop for grid-wide lockstep
// (R5 showed desynchronized tile streams regress L2/L3 sharing).

#define B_ 16
#define L_ 512
#define H_ 8
#define KST 72   // K LDS row stride (shorts)
#define VST 72   // V^T LDS row stride (shorts)
#define WST 36   // W LDS row stride (dwords), 16 rows/wave

typedef __attribute__((ext_vector_type(8))) short bf16x8;
typedef __attribute__((ext_vector_type(4))) float f32x4;
union FR { bf16x8 v; unsigned u[4]; uint4 q4; };

static __device__ __forceinline__ unsigned fbits(float x){union{float f;unsigned u;}c;c.f=x;return c.u;}
static __device__ __forceinline__ float tvf(float x){union{unsigned u;float f;}c;c.u=fbits(x)&0xFFFF0000u;return c.f;}
// pack trunc-bf16(a) | trunc-bf16(b)<<16 in one v_perm_b32
static __device__ __forceinline__ unsigned pk2(float a,float b){return __builtin_amdgcn_perm(fbits(b),fbits(a),0x07060302u);}

__global__ __launch_bounds__(256,4) void anomaly_attn(
    const float* __restrict__ Q, const float* __restrict__ K,
    const float* __restrict__ V, const float* __restrict__ Sig,
    const float* __restrict__ Gate, float* __restrict__ Out)
{
  __shared__ unsigned short Klds[64*KST];   // 9216 B
  __shared__ unsigned short Vlds[64*VST];   // 9216 B (V^T, granule-swizzled)
  __shared__ unsigned We[4][16][WST];       // 9216 B packed e pairs
  __shared__ unsigned Wp[4][16][WST];       // 9216 B packed p pairs

  const int tid=threadIdx.x, lane=tid&63, wid=tid>>6, q=lane>>4, c=lane&15;
  const int idx=blockIdx.x, bh=idx&127, t=idx>>7, h=bh&7, b=bh>>3;
  const int l0w = t*64 + wid*16;            // wave's 16 l-rows: l = l0w + c
  const size_t bh_off = ((size_t)b*L_*H_ + h)*64;
  const float* __restrict__ Qb=Q+bh_off;
  const float* __restrict__ Kb=K+bh_off;
  const float* __restrict__ Vb=V+bh_off;

  // ---- Q as B-operand frag: lane c -> l, quad*8+j -> e ----
  bf16x8 qf[2];
  {
    const float* qrow = Qb + (size_t)(l0w+c)*512;
    #pragma unroll
    for (int ks=0; ks<2; ++ks) {
      const float4 a = *(const float4*)(qrow + ks*32 + q*8);
      const float4 d4 = *(const float4*)(qrow + ks*32 + q*8 + 4);
      FR f;
      f.u[0]=pk2(a.x,a.y);  f.u[1]=pk2(a.z,a.w);
      f.u[2]=pk2(d4.x,d4.y); f.u[3]=pk2(d4.z,d4.w);
      qf[ks]=f.v;
    }
  }

  // ---- per-lane prior constants (row l = l0w + c) ----
  const float sgv = Sig[((size_t)b*L_ + l0w + c)*H_ + h];
  float sg = 1.f/(1.f+__expf(-5.f*sgv)) + 1e-5f;
  sg = exp2f(sg*1.5849625007211562f) - 1.f;          // 3^sg - 1
  const float invs = 0.3989422804014327f/sg;
  const float i2s2 = (0.5f/(sg*sg))*1.44269504088896f;

  float eP=0.f, pP=0.f;
  f32x4 accA[4], accB[4];
  #pragma unroll
  for (int n=0;n<4;++n){accA[n]=(f32x4)0.f;accB[n]=(f32x4)0.f;}

  const int kr=tid>>2, kcb=tid&3, srp=tid>>3, scb=tid&7;
  const int swz = (c&3)<<3;                 // W column XOR swizzle

  for (int tile=0; tile<8; ++tile) {
    const int s0=tile*64;
    const bool live = tile<=t, diag = tile==t;   // block-uniform
    const int delta = s0 - l0w;                  // wave-uniform
    __syncthreads();
    { // ---- V stage (all tiles: uniform lockstep): V^T bf16 pairs ----
      const float* vp = Vb + (size_t)(s0+2*srp)*512 + scb*8;
      const float4 va0=((const float4*)vp)[0], va1=((const float4*)vp)[1];
      const float4 vb0=((const float4*)(vp+512))[0], vb1=((const float4*)(vp+512))[1];
      const float lo[8]={va0.x,va0.y,va0.z,va0.w,va1.x,va1.y,va1.z,va1.w};
      const float hi[8]={vb0.x,vb0.y,vb0.z,vb0.w,vb1.x,vb1.y,vb1.z,vb1.w};
      const int gp=(srp>>2)^scb, rpl=srp&3;
      #pragma unroll
      for (int i=0;i<8;++i){
        unsigned* p=(unsigned*)&Vlds[(scb*8+i)*VST + (gp<<3)];
        p[rpl]=pk2(lo[i],hi[i]);
      }
    }
    if (live) { // ---- K stage: rows [s][e] bf16 ----
      const float* kp = Kb + (size_t)(s0+kr)*512 + kcb*16;
      const float4 ka=((const float4*)kp)[0], kb2=((const float4*)kp)[1];
      const float4 kc2=((const float4*)kp)[2], kd2=((const float4*)kp)[3];
      uint4 w0,w1;
      w0.x=pk2(ka.x,ka.y);  w0.y=pk2(ka.z,ka.w);
      w0.z=pk2(kb2.x,kb2.y); w0.w=pk2(kb2.z,kb2.w);
      w1.x=pk2(kc2.x,kc2.y); w1.y=pk2(kc2.z,kc2.w);
      w1.z=pk2(kd2.x,kd2.y); w1.w=pk2(kd2.z,kd2.w);
      uint4* dst=(uint4*)&Klds[kr*KST + kcb*16];
      dst[0]=w0; dst[1]=w1;
    }
    __syncthreads();

    // ---- e path: scores S^T then packed bf16 into We (D-layout == B-layout) ----
    int ks2max = -1;
    if (live) {
      const int ntmax = diag ? wid : 3;         // s-chunks with any e!=0
      ks2max = diag ? (wid>>1) : 1;             // s-32-chunks for PV
      f32x4 sacc[4];
      #pragma unroll
      for (int nt=0;nt<4;++nt) if (nt<=ntmax) {
        f32x4 s=(f32x4)0.f;
        #pragma unroll
        for (int ks=0;ks<2;++ks){
          const bf16x8 kf=*(const bf16x8*)&Klds[(nt*16+c)*KST + ks*32 + q*8];
          s=__builtin_amdgcn_mfma_f32_16x16x32_bf16(kf,qf[ks],s,0,0,0); // A=K(m=s),B=Q(n=l)
        }
        sacc[nt]=s;
      }
      #pragma unroll
      for (int nt=0;nt<4;++nt) {
        if (nt<=ntmax) {
          float ev[4];
          #pragma unroll
          for (int r=0;r<4;++r) ev[r]=exp2f(sacc[nt][r]*0.180336880110323f); // exp(s/8)
          if (diag && nt==wid) {                 // per-element causal mask
            #pragma unroll
            for (int r=0;r<4;++r) if (4*q+r > c) ev[r]=0.f;
          }
          #pragma unroll
          for (int r=0;r<4;++r) eP += tvf(ev[r]);  // sum == MFMA operand
          uint2 w; w.x=pk2(ev[0],ev[1]); w.y=pk2(ev[2],ev[3]);
          *(uint2*)&We[wid][c][(nt*8+2*q)^swz]=w;
        } else if (nt <= 2*ks2max+1) {           // zero-fill read-covered chunk
          uint2 z; z.x=0u; z.y=0u;
          *(uint2*)&We[wid][c][(nt*8+2*q)^swz]=z;
        }
      }
    }

    // ---- p path: band-limited prior (exact f32 underflow outside) ----
    const bool bk0 = (delta    >= -95) && (delta    <= 79);
    const bool bk1 = (delta+32 >= -95) && (delta+32 <= 79);
    if (bk0||bk1) {
      #pragma unroll
      for (int nt=0;nt<4;++nt) {
        const bool need = (nt>>1) ? bk1 : bk0;
        if (need) {
          const int dbase = delta + nt*16;
          if (dbase>=-79 && dbase<=79) {
            float pv[4];
            #pragma unroll
            for (int r=0;r<4;++r){
              const float dd=(float)((c - 4*q - r) - dbase);  // l - s
              pv[r]=invs*exp2f(-dd*dd*i2s2);
              pP += tvf(pv[r]);
            }
            uint2 w; w.x=pk2(pv[0],pv[1]); w.y=pk2(pv[2],pv[3]);
            *(uint2*)&Wp[wid][c][(nt*8+2*q)^swz]=w;
          } else {
            uint2 z; z.x=0u; z.y=0u;
            *(uint2*)&Wp[wid][c][(nt*8+2*q)^swz]=z;
          }
        }
      }
    }
    asm volatile("s_waitcnt lgkmcnt(0)" ::: "memory");

    // ---- PV: A = V^T (m=d,k=s), B = W (k=s,n=l) ----
    FR ef[2], pf[2];
    #pragma unroll
    for (int k2=0;k2<2;++k2){
      const int col=(k2*16+4*q)^swz;
      if (k2<=ks2max)        ef[k2].q4 = *(const uint4*)&We[wid][c][col];
      if (k2 ? bk1 : bk0)    pf[k2].q4 = *(const uint4*)&Wp[wid][c][col];
    }
    #pragma unroll
    for (int nd=0;nd<4;++nd){
      const int d=nd*16+c, dg7=(d>>3)&7;
      #pragma unroll
      for (int k2=0;k2<2;++k2){
        const bool pb = k2 ? bk1 : bk0;
        if (k2<=ks2max || pb) {
          const int g2=((k2<<2)+q)^dg7;
          const bf16x8 vf=*(const bf16x8*)&Vlds[d*VST + (g2<<3)];
          if (k2<=ks2max) accA[nd]=__builtin_amdgcn_mfma_f32_16x16x32_bf16(vf,ef[k2].v,accA[nd],0,0,0);
          if (pb)         accB[nd]=__builtin_amdgcn_mfma_f32_16x16x32_bf16(vf,pf[k2].v,accB[nd],0,0,0);
        }
      }
    }
  }

  // ---- epilogue: 4-lane (quad) reduce, per-lane scalars, float4 stores ----
  eP += __shfl_xor(eP,16,64); eP += __shfl_xor(eP,32,64);
  pP += __shfl_xor(pP,16,64); pP += __shfl_xor(pP,32,64);
  float g=Gate[h]; g=1.f/(1.f+__expf(-g));
  const float cA=g/eP;                       // E>0 (diagonal always live)
  const float cB=(1.f-g)/(pP+1e-8f);
  const float Sf=g+(1.f-g)*(pP/(pP+1e-8f));
  const float nf=1.f/(Sf+1e-8f);
  #pragma unroll
  for (int nd=0;nd<4;++nd){
    float4 o;
    o.x=(cA*accA[nd][0]+cB*accB[nd][0])*nf;
    o.y=(cA*accA[nd][1]+cB*accB[nd][1])*nf;
    o.z=(cA*accA[nd][2]+cB*accB[nd][2])*nf;
    o.w=(cA*accA[nd][3]+cB*accB[nd][3])*nf;
    *(float4*)&Out[bh_off + (size_t)(l0w+c)*512 + nd*16 + 4*q] = o;
  }
}

extern "C" void kernel_launch(void* const* d_in, const int* in_sizes, int n_in,
                              void* d_out, int out_size, void* d_ws, size_t ws_size,
                              hipStream_t stream) {
    const float* Q    = (const float*)d_in[0];
    const float* K    = (const float*)d_in[1];
    const float* V    = (const float*)d_in[2];
    const float* Sig  = (const float*)d_in[3];
    const float* Gate = (const float*)d_in[4];
    // d_in[5] = attn_mask: deterministic causal triu — not read.
    float* Out = (float*)d_out;

    dim3 grid(8 * B_ * H_);   // 1024 blocks: idx = t*128 + bh (XCD-affine)
    anomaly_attn<<<grid, 256, 0, stream>>>(Q, K, V, Sig, Gate, Out);
}